// Round 8
// baseline (158.759 us; speedup 1.0000x reference)
//
#include <hip/hip_runtime.h>

// Problem constants (from reference): B=16, C=1, H=1024, W=1024, fp32.
#define HH 1024
#define WW 1024
#define RPB 4            // rows per block: 1024 threads = 4 rows x 256 thr/row
#define NT 1024

__device__ __forceinline__ float fmax3(float a, float b, float c) {
    return fmaxf(a, fmaxf(b, c));
}

__device__ __forceinline__ float loss_elem(float x, float t, float dil) {
    // target/dilated are exactly binary {0,1}: weight = 1 + 4*dil + 15*t
    float w = fmaf(15.0f, t, fmaf(4.0f, dil, 1.0f));
    // BCE with logits: max(x,0) - x*t + log1p(exp(-|x|))
    // softplus via HW v_exp_f32 / v_log_f32 (absmax 0.0 since R2).
    float a  = fabsf(x);
    float sp = __logf(1.0f + __expf(-a));
    return w * (fmaxf(x, 0.0f) - x * t + sp);
}

template <bool PER_WAVE>
__global__ __launch_bounds__(NT) void dilatedweightBCE_main(
        const float* __restrict__ pred,
        const float* __restrict__ target,
        float* __restrict__ partial) {
    // 1024-thread blocks: 2 blocks/CU -> 32 waves/CU (100% occupancy
    // potential; R6 plateaued at 58% with 256-thr blocks). One row x float4
    // per thread keeps VGPR ~30 and the dependence graph shallow; 4
    // independent global loads in flight per thread. Halo for the 2
    // wave-boundary lanes hoisted. PER_WAVE tail: no LDS, no barrier.
    __shared__ float swave[NT / 64];

    const int t    = threadIdx.x;
    const int lane = t & 63;
    const int w16  = t >> 6;                 // wave id in block (0..15)
    const int rin  = t >> 8;                 // row within block (wave-uniform)
    const int c    = (t & 255) * 4;          // first column of this thread
    const int b    = blockIdx.y;
    const int h    = blockIdx.x * RPB + rin;

    const float* timg = target + (size_t)b * HH * WW;
    const size_t rowoff = (size_t)h * WW;
    const bool has_up = (h > 0);             // wave-uniform branches
    const bool has_dn = (h < HH - 1);
    const float4 zero = make_float4(0.0f, 0.0f, 0.0f, 0.0f);

    // ---- independent loads, all issued up front ----
    float4 tmid = *(const float4*)(timg + rowoff + c);
    float4 tup  = has_up ? *(const float4*)(timg + rowoff - WW + c) : zero;
    float4 tdn  = has_dn ? *(const float4*)(timg + rowoff + WW + c) : zero;
    float4 x    = *(const float4*)(pred + (size_t)b * HH * WW + rowoff + c);

    float halo = 0.0f;                       // vmax at col c-1 (lane0) / c+4 (lane63)
    if (lane == 0 || lane == 63) {
        const int pc = (lane == 0) ? c - 1 : c + 4;
        if (pc >= 0 && pc < WW) {
            float v = timg[rowoff + pc];
            if (has_up) v = fmaxf(v, timg[rowoff - WW + pc]);
            if (has_dn) v = fmaxf(v, timg[rowoff + WW + pc]);
            halo = v;
        }
    }

    // ---- dilation + loss ----
    float4 vm = make_float4(fmax3(tup.x, tmid.x, tdn.x),
                            fmax3(tup.y, tmid.y, tdn.y),
                            fmax3(tup.z, tmid.z, tdn.z),
                            fmax3(tup.w, tmid.w, tdn.w));

    float l  = __shfl_up(vm.w, 1);
    float rr = __shfl_down(vm.x, 1);
    if (lane == 0)  l  = halo;
    if (lane == 63) rr = halo;

    float d0 = fmax3(l,    vm.x, vm.y);
    float d1 = fmax3(vm.x, vm.y, vm.z);
    float d2 = fmax3(vm.y, vm.z, vm.w);
    float d3 = fmax3(vm.z, vm.w, rr);

    float s = 0.0f;
    s += loss_elem(x.x, tmid.x, d0);
    s += loss_elem(x.y, tmid.y, d1);
    s += loss_elem(x.z, tmid.z, d2);
    s += loss_elem(x.w, tmid.w, d3);

    // ---- wave reduction ----
    #pragma unroll
    for (int off = 32; off > 0; off >>= 1)
        s += __shfl_down(s, off);

    if (PER_WAVE) {
        // one disjoint slot per wave: no LDS, no barrier, no contention
        if (lane == 0)
            partial[((size_t)blockIdx.y * gridDim.x + blockIdx.x) * (NT / 64) + w16] = s;
    } else {
        if (lane == 0) swave[w16] = s;
        __syncthreads();
        if (t < 64) {
            float v = (lane < NT / 64) ? swave[lane] : 0.0f;
            #pragma unroll
            for (int off = 8; off > 0; off >>= 1)
                v += __shfl_down(v, off);
            if (lane == 0)
                partial[(size_t)blockIdx.y * gridDim.x + blockIdx.x] = v;
        }
    }
}

__global__ __launch_bounds__(NT) void dilatedweightBCE_reduce(
        const float* __restrict__ partial,
        float* __restrict__ out,
        int npart4,            // number of float4 chunks
        float inv_n) {
    __shared__ float swave[NT / 64];
    const int t = threadIdx.x;

    float s = 0.0f;
    const float4* p4 = (const float4*)partial;
    for (int i = t; i < npart4; i += NT) {
        float4 v = p4[i];
        s += v.x + v.y + v.z + v.w;
    }

    #pragma unroll
    for (int off = 32; off > 0; off >>= 1)
        s += __shfl_down(s, off);

    const int lane = t & 63;
    if (lane == 0) swave[t >> 6] = s;
    __syncthreads();
    if (t == 0) {
        float tot = 0.0f;
        #pragma unroll
        for (int i = 0; i < NT / 64; ++i) tot += swave[i];
        out[0] = tot * inv_n;
    }
}

extern "C" void kernel_launch(void* const* d_in, const int* in_sizes, int n_in,
                              void* d_out, int out_size, void* d_ws, size_t ws_size,
                              hipStream_t stream) {
    const float* pred   = (const float*)d_in[0];
    const float* target = (const float*)d_in[1];
    float* out     = (float*)d_out;
    float* partial = (float*)d_ws;

    const int n  = in_sizes[0];              // B*C*H*W
    const int Bn = n / (HH * WW);            // batch (16)
    const int nblocks = (HH / RPB) * Bn;     // 4096

    dim3 grid(HH / RPB, Bn);
    const size_t need = (size_t)nblocks * (NT / 64) * sizeof(float);  // 256 KB
    if (ws_size >= need) {
        dilatedweightBCE_main<true><<<grid, NT, 0, stream>>>(pred, target, partial);
        dilatedweightBCE_reduce<<<1, NT, 0, stream>>>(partial, out,
                                                      nblocks * (NT / 64) / 4,
                                                      1.0f / (float)n);
    } else {
        dilatedweightBCE_main<false><<<grid, NT, 0, stream>>>(pred, target, partial);
        dilatedweightBCE_reduce<<<1, NT, 0, stream>>>(partial, out,
                                                      nblocks / 4, 1.0f / (float)n);
    }
}

// Round 9
// 146.283 us; speedup vs baseline: 1.0853x; 1.0853x over previous
//
#include <hip/hip_runtime.h>

// Problem constants (from reference): B=16, C=1, H=1024, W=1024, fp32.
#define HH 1024
#define WW 1024
#define BAND 8           // output rows per block
#define NT 512           // threads per block
#define LDSF ((BAND + 2) * WW)   // 10 rows * 1024 floats = 40960 B LDS

__device__ __forceinline__ float fmax3(float a, float b, float c) {
    return fmaxf(a, fmaxf(b, c));
}

__device__ __forceinline__ float loss_elem(float x, float t, float dil) {
    // target/dilated are exactly binary {0,1}: weight = 1 + 4*dil + 15*t
    float w = fmaf(15.0f, t, fmaf(4.0f, dil, 1.0f));
    // BCE with logits: max(x,0) - x*t + log1p(exp(-|x|))
    // softplus via HW v_exp_f32 / v_log_f32 (absmax 0.0 since R2).
    float a  = fabsf(x);
    float sp = __logf(1.0f + __expf(-a));
    return w * (fmaxf(x, 0.0f) - x * t + sp);
}

__device__ __forceinline__ void load_to_lds16(const float* g, float* l) {
    // async global->LDS, 16B per lane; dest = wave-uniform base + lane*16,
    // which our flat contiguous layout satisfies (lds idx == source idx).
    __builtin_amdgcn_global_load_lds(
        (const __attribute__((address_space(1))) void*)g,
        (__attribute__((address_space(3))) void*)l,
        16, 0, 0);
}

template <bool PER_WAVE>
__global__ __launch_bounds__(NT) void dilatedweightBCE_main(
        const float* __restrict__ pred,
        const float* __restrict__ target,
        float* __restrict__ partial) {
    // One block per (image b, 8-row band). Stage 10 target rows (band+halo)
    // into LDS via global_load_lds: requested bytes drop to 1.25x target +
    // 1x pred = 144 MB (vs R6 168 / R8 256), and the 5 staging loads per
    // thread consume NO result VGPRs -> all 9 global loads in flight.
    // All kernels R4-R8 plateaued at ~4-5 TB/s *requested* bytes regardless
    // of occupancy/warmth; fewer requested bytes is the remaining lever.
    __shared__ float lds[LDSF];   // rows h0-1 .. h0+8, flat contiguous

    const int t    = threadIdx.x;
    const int lane = t & 63;
    const int wv   = t >> 6;                 // wave id 0..7
    const int b    = blockIdx.y;
    const int h0   = blockIdx.x * BAND;

    const float* timg = target + (size_t)b * HH * WW;
    const float* pimg = pred   + (size_t)b * HH * WW;

    // ---- zero-fill out-of-image halo rows (disjoint from staged region) ----
    const float4 zero4 = make_float4(0.0f, 0.0f, 0.0f, 0.0f);
    if (h0 == 0 && t < WW / 4) ((float4*)lds)[t] = zero4;
    if (h0 + BAND == HH && t >= NT - WW / 4)
        ((float4*)(lds + (BAND + 1) * WW))[t - (NT - WW / 4)] = zero4;

    // ---- async-stage 10 target rows; rows are contiguous in memory ----
    const float* src = timg + (long long)(h0 - 1) * WW;   // row h0-1 base
    #pragma unroll
    for (int k = 0; k < LDSF / (NT * 4); ++k) {           // 5 chunks
        const int idx = k * NT + t;                       // float4 index
        const int r   = idx >> 8;                         // lds row 0..9
        const bool valid = (h0 - 1 + r >= 0) && (h0 - 1 + r < HH);
        if (valid) load_to_lds16(src + (size_t)idx * 4, lds + (size_t)idx * 4);
    }

    // ---- pred loads to registers, overlapping the staging ----
    const int rg4 = (t >> 8) * 4;            // row group: 0 or 4 (wave-uniform)
    const int c   = (t & 255) * 4;           // first column of this thread
    float4 xr[4];
    #pragma unroll
    for (int j = 0; j < 4; ++j)
        xr[j] = *(const float4*)(pimg + (size_t)(h0 + rg4 + j) * WW + c);

    __syncthreads();   // drains vmcnt(0): staging + pred complete

    // ---- halo column for wave-boundary lanes (from LDS) ----
    float halo[4];
    #pragma unroll
    for (int j = 0; j < 4; ++j) halo[j] = 0.0f;
    if (lane == 0 || lane == 63) {
        const int pc = (lane == 0) ? c - 1 : c + 4;
        if (pc >= 0 && pc < WW) {
            float hv[6];
            #pragma unroll
            for (int i = 0; i < 6; ++i)
                hv[i] = lds[(rg4 + i) * WW + pc];
            #pragma unroll
            for (int j = 0; j < 4; ++j)
                halo[j] = fmax3(hv[j], hv[j + 1], hv[j + 2]);
        }
    }

    // ---- 6 aligned ds_read_b128, rolling vertical max over 4 output rows ----
    float4 R[6];
    #pragma unroll
    for (int i = 0; i < 6; ++i)
        R[i] = *(const float4*)(lds + (rg4 + i) * WW + c);

    float s = 0.0f;
    #pragma unroll
    for (int j = 0; j < 4; ++j) {
        float4 a = R[j], m = R[j + 1], d = R[j + 2];
        float4 vm = make_float4(fmax3(a.x, m.x, d.x), fmax3(a.y, m.y, d.y),
                                fmax3(a.z, m.z, d.z), fmax3(a.w, m.w, d.w));

        float l  = __shfl_up(vm.w, 1);
        float rr = __shfl_down(vm.x, 1);
        if (lane == 0)  l  = halo[j];
        if (lane == 63) rr = halo[j];

        float d0 = fmax3(l,    vm.x, vm.y);
        float d1 = fmax3(vm.x, vm.y, vm.z);
        float d2 = fmax3(vm.y, vm.z, vm.w);
        float d3 = fmax3(vm.z, vm.w, rr);

        float4 x = xr[j];
        s += loss_elem(x.x, m.x, d0);
        s += loss_elem(x.y, m.y, d1);
        s += loss_elem(x.z, m.z, d2);
        s += loss_elem(x.w, m.w, d3);
    }

    // ---- wave reduction ----
    #pragma unroll
    for (int off = 32; off > 0; off >>= 1)
        s += __shfl_down(s, off);

    const size_t bid = (size_t)blockIdx.y * gridDim.x + blockIdx.x;
    if (PER_WAVE) {
        if (lane == 0) partial[bid * 8 + wv] = s;   // no LDS, no extra barrier
    } else {
        // reuse the (now-dead) staging buffer for the cross-wave reduce
        __syncthreads();
        if (lane == 0) lds[wv] = s;
        __syncthreads();
        if (t == 0) {
            float tot = 0.0f;
            #pragma unroll
            for (int i = 0; i < 8; ++i) tot += lds[i];
            partial[bid] = tot;
        }
    }
}

__global__ __launch_bounds__(1024) void dilatedweightBCE_reduce(
        const float* __restrict__ partial,
        float* __restrict__ out,
        int npart4,            // number of float4 chunks
        float inv_n) {
    __shared__ float swave[16];
    const int t = threadIdx.x;

    float s = 0.0f;
    const float4* p4 = (const float4*)partial;
    for (int i = t; i < npart4; i += 1024) {
        float4 v = p4[i];
        s += v.x + v.y + v.z + v.w;
    }

    #pragma unroll
    for (int off = 32; off > 0; off >>= 1)
        s += __shfl_down(s, off);

    const int lane = t & 63;
    if (lane == 0) swave[t >> 6] = s;
    __syncthreads();
    if (t == 0) {
        float tot = 0.0f;
        #pragma unroll
        for (int i = 0; i < 16; ++i) tot += swave[i];
        out[0] = tot * inv_n;
    }
}

extern "C" void kernel_launch(void* const* d_in, const int* in_sizes, int n_in,
                              void* d_out, int out_size, void* d_ws, size_t ws_size,
                              hipStream_t stream) {
    const float* pred   = (const float*)d_in[0];
    const float* target = (const float*)d_in[1];
    float* out     = (float*)d_out;
    float* partial = (float*)d_ws;

    const int n  = in_sizes[0];              // B*C*H*W
    const int Bn = n / (HH * WW);            // batch (16)
    const int nblocks = (HH / BAND) * Bn;    // 2048

    dim3 grid(HH / BAND, Bn);
    const size_t need = (size_t)nblocks * 8 * sizeof(float);   // 64 KB
    if (ws_size >= need) {
        dilatedweightBCE_main<true><<<grid, NT, 0, stream>>>(pred, target, partial);
        dilatedweightBCE_reduce<<<1, 1024, 0, stream>>>(partial, out,
                                                        nblocks * 8 / 4,
                                                        1.0f / (float)n);
    } else {
        dilatedweightBCE_main<false><<<grid, NT, 0, stream>>>(pred, target, partial);
        dilatedweightBCE_reduce<<<1, 1024, 0, stream>>>(partial, out,
                                                        nblocks / 4,
                                                        1.0f / (float)n);
    }
}

// Round 10
// 141.903 us; speedup vs baseline: 1.1188x; 1.0309x over previous
//
#include <hip/hip_runtime.h>

// Problem constants (from reference): B=16, C=1, H=1024, W=1024, fp32.
#define HH 1024
#define WW 1024
#define BAND 8           // rows per block; thread = 8 rows x float4 strip
#define NT 256

__device__ __forceinline__ float fmax3(float a, float b, float c) {
    return fmaxf(a, fmaxf(b, c));
}

__device__ __forceinline__ float loss_elem(float x, float t, float dil) {
    // target/dilated are exactly binary {0,1}: weight = 1 + 4*dil + 15*t
    float w = fmaf(15.0f, t, fmaf(4.0f, dil, 1.0f));
    // BCE with logits: max(x,0) - x*t + log1p(exp(-|x|))
    // softplus via HW v_exp_f32 / v_log_f32 (absmax 0.0 since R2).
    float a  = fabsf(x);
    float sp = __logf(1.0f + __expf(-a));
    return w * (fmaxf(x, 0.0f) - x * t + sp);
}

template <bool PER_WAVE>
__global__ __launch_bounds__(NT, 4) void dilatedweightBCE_main(
        const float* __restrict__ pred,
        const float* __restrict__ target,
        float* __restrict__ partial) {
    // MAX-MLP experiment: R6/R9 tied at ~43.5us with ~100-160 loads in
    // flight per CU (R6's VGPR=32 proves its 10 loads were serialized by
    // the allocator's 8-wave occupancy target). launch_bounds(256,4) sets
    // the RP target to 128 VGPR so ALL 18 float4 loads/thread stay live;
    // 2048 blocks keeps 2 resident batches (R7's mistake was 1024 blocks).
    // XCD swizzle: each XCD owns a 128-row slab per image -> band-halo
    // re-reads (rows shared by adjacent bands) hit the local L2.
    __shared__ float swave[NT / 64];

    const int t    = threadIdx.x;
    const int lane = t & 63;
    const int wv   = t >> 6;
    const int c    = t * 4;                  // column strip (NT*4 == WW)

    // --- XCD-contiguous swizzle: l -> (img, h0) ---
    const int l    = blockIdx.x;             // [0, 2048)
    const int xcd  = l & 7;
    const int j    = l >> 3;                 // [0, 256)
    const int img  = j >> 4;                 // [0, 16)
    const int band = j & 15;                 // [0, 16)
    const int h0   = (xcd * 16 + band) * BAND;   // XCD x owns rows [128x,128x+128)

    const float* timg = target + (size_t)img * HH * WW;
    const float* pimg = pred   + (size_t)img * HH * WW;
    const float4 zero = make_float4(0.0f, 0.0f, 0.0f, 0.0f);

    // ---- ALL 18 independent loads issued before any use ----
    float4 tr[BAND + 2];                     // target rows h0-1 .. h0+BAND
    tr[0] = (h0 > 0) ? *(const float4*)(timg + (size_t)(h0 - 1) * WW + c) : zero;
    #pragma unroll
    for (int r = 0; r < BAND; ++r)
        tr[r + 1] = *(const float4*)(timg + (size_t)(h0 + r) * WW + c);
    tr[BAND + 1] = (h0 + BAND < HH)
                 ? *(const float4*)(timg + (size_t)(h0 + BAND) * WW + c) : zero;

    float4 xr[BAND];                         // pred rows h0 .. h0+BAND-1
    #pragma unroll
    for (int r = 0; r < BAND; ++r)
        xr[r] = *(const float4*)(pimg + (size_t)(h0 + r) * WW + c);

    // ---- halo column for wave-boundary lanes (L1/L2 hits, 2 lanes/wave) ----
    float halo[BAND];
    #pragma unroll
    for (int r = 0; r < BAND; ++r) halo[r] = 0.0f;
    if (lane == 0 || lane == 63) {
        const int pc = (lane == 0) ? c - 1 : c + 4;
        if (pc >= 0 && pc < WW) {
            float hv[BAND + 2];
            hv[0] = (h0 > 0) ? timg[(size_t)(h0 - 1) * WW + pc] : 0.0f;
            #pragma unroll
            for (int r = 0; r < BAND; ++r)
                hv[r + 1] = timg[(size_t)(h0 + r) * WW + pc];
            hv[BAND + 1] = (h0 + BAND < HH)
                         ? timg[(size_t)(h0 + BAND) * WW + pc] : 0.0f;
            #pragma unroll
            for (int r = 0; r < BAND; ++r)
                halo[r] = fmax3(hv[r], hv[r + 1], hv[r + 2]);
        }
    }

    // ---- dilation + loss, row by row (row j needs only tr[j..j+2]) ----
    float s = 0.0f;
    #pragma unroll
    for (int r = 0; r < BAND; ++r) {
        float4 a = tr[r], m = tr[r + 1], d = tr[r + 2];
        float4 vm = make_float4(fmax3(a.x, m.x, d.x), fmax3(a.y, m.y, d.y),
                                fmax3(a.z, m.z, d.z), fmax3(a.w, m.w, d.w));

        float lft = __shfl_up(vm.w, 1);
        float rgt = __shfl_down(vm.x, 1);
        if (lane == 0)  lft = halo[r];
        if (lane == 63) rgt = halo[r];

        float d0 = fmax3(lft,  vm.x, vm.y);
        float d1 = fmax3(vm.x, vm.y, vm.z);
        float d2 = fmax3(vm.y, vm.z, vm.w);
        float d3 = fmax3(vm.z, vm.w, rgt);

        float4 x = xr[r];
        s += loss_elem(x.x, m.x, d0);
        s += loss_elem(x.y, m.y, d1);
        s += loss_elem(x.z, m.z, d2);
        s += loss_elem(x.w, m.w, d3);
    }

    // ---- wave reduction ----
    #pragma unroll
    for (int off = 32; off > 0; off >>= 1)
        s += __shfl_down(s, off);

    if (PER_WAVE) {
        if (lane == 0)
            partial[(size_t)l * (NT / 64) + wv] = s;   // no barrier, no LDS
    } else {
        if (lane == 0) swave[wv] = s;
        __syncthreads();
        if (t == 0) {
            float tot = 0.0f;
            #pragma unroll
            for (int i = 0; i < NT / 64; ++i) tot += swave[i];
            partial[l] = tot;
        }
    }
}

__global__ __launch_bounds__(1024) void dilatedweightBCE_reduce(
        const float* __restrict__ partial,
        float* __restrict__ out,
        int npart4,            // number of float4 chunks
        float inv_n) {
    __shared__ float swave[16];
    const int t = threadIdx.x;

    float s = 0.0f;
    const float4* p4 = (const float4*)partial;
    for (int i = t; i < npart4; i += 1024) {
        float4 v = p4[i];
        s += v.x + v.y + v.z + v.w;
    }

    #pragma unroll
    for (int off = 32; off > 0; off >>= 1)
        s += __shfl_down(s, off);

    const int lane = t & 63;
    if (lane == 0) swave[t >> 6] = s;
    __syncthreads();
    if (t == 0) {
        float tot = 0.0f;
        #pragma unroll
        for (int i = 0; i < 16; ++i) tot += swave[i];
        out[0] = tot * inv_n;
    }
}

extern "C" void kernel_launch(void* const* d_in, const int* in_sizes, int n_in,
                              void* d_out, int out_size, void* d_ws, size_t ws_size,
                              hipStream_t stream) {
    const float* pred   = (const float*)d_in[0];
    const float* target = (const float*)d_in[1];
    float* out     = (float*)d_out;
    float* partial = (float*)d_ws;

    const int n  = in_sizes[0];              // B*C*H*W
    const int Bn = n / (HH * WW);            // batch (16)
    const int nblocks = (HH / BAND) * Bn;    // 2048

    const size_t need = (size_t)nblocks * (NT / 64) * sizeof(float);  // 32 KB
    if (ws_size >= need) {
        dilatedweightBCE_main<true><<<nblocks, NT, 0, stream>>>(pred, target, partial);
        dilatedweightBCE_reduce<<<1, 1024, 0, stream>>>(partial, out,
                                                        nblocks * (NT / 64) / 4,
                                                        1.0f / (float)n);
    } else {
        dilatedweightBCE_main<false><<<nblocks, NT, 0, stream>>>(pred, target, partial);
        dilatedweightBCE_reduce<<<1, 1024, 0, stream>>>(partial, out,
                                                        nblocks / 4,
                                                        1.0f / (float)n);
    }
}